// Round 23
// baseline (226.849 us; speedup 1.0000x reference)
//
#include <hip/hip_runtime.h>
#include <hip/hip_bf16.h>
#include <math.h>

namespace {
constexpr int DD = 2048;          // feature dim
constexpr int EE = 64;            // experts
constexpr int KK = 8;             // top-k
constexpr int TPB = 64;           // tokens per block
constexpr int MS = 128;           // K per mega-step
constexpr int NMEGA = DD / MS;    // 16
constexpr int NTH = 256;          // 4 waves
constexpr int XB = TPB * MS * 4;  // 32768 B per x stage buffer (f32)
constexpr float TAU = 2e-4f;      // ambiguity gap threshold (~30 sigma of split-bf16 error)
}

typedef __attribute__((ext_vector_type(8))) short short8;   // 8 bf16 (4 VGPRs)
typedef __attribute__((ext_vector_type(4))) float f32x4;

#define RES(t, e) res[(t) * 129 + (e)]

__device__ inline void split_bf16(float v, ushort& h, ushort& l) {
    __hip_bfloat16 hb = __float2bfloat16(v);
    float hf = __bfloat162float(hb);
    __hip_bfloat16 lb = __float2bfloat16(v - hf);
    h = __builtin_bit_cast(ushort, hb);
    l = __builtin_bit_cast(ushort, lb);
}

__device__ inline void conv_tile(const float4& A, const float4& B, short8& hi, short8& lo) {
    const float f[8] = {A.x, A.y, A.z, A.w, B.x, B.y, B.z, B.w};
#pragma unroll
    for (int i = 0; i < 8; ++i) {
        ushort h, l;
        split_bf16(f[i], h, l);
        hi[i] = (short)h;
        lo[i] = (short)l;
    }
}

// T14 async-STAGE split: XLOAD issues 8 coalesced float4 reads of x(m_) into regs
// (right after the barrier); XSTORE writes them to LDS at swizzled positions
// (just before the barrier) — HBM latency hides under the mega's compute.
// LDS layout identical to prior rounds: unit u of row r stored at position u^(r&7).
#define XLOAD(m_)                                                                      \
    do {                                                                               \
        _Pragma("unroll")                                                              \
        for (int j = 0; j < 8; ++j) {                                                  \
            const int row_ = (w * 8 + j) * 2 + (lane >> 5);                            \
            const int u_   = lane & 31;                                                \
            xr[j] = *reinterpret_cast<const float4*>(                                  \
                x + (tok0 + row_) * (long)DD + (long)(m_) * MS + (u_ << 2));           \
        }                                                                              \
    } while (0)

#define XSTORE(c_)                                                                     \
    do {                                                                               \
        unsigned char* xb_ = smem + (c_) * XB;                                         \
        _Pragma("unroll")                                                              \
        for (int j = 0; j < 8; ++j) {                                                  \
            const int row_ = (w * 8 + j) * 2 + (lane >> 5);                            \
            const int u_   = lane & 31;                                                \
            *reinterpret_cast<float4*>(                                                \
                xb_ + row_ * 512 + ((u_ ^ (row_ & 7)) << 4)) = xr[j];                  \
        }                                                                              \
    } while (0)

// W fragment load for (mega m, substep ss) into 8 uint4 (4 et x hi/lo)
#define LOADW(dst_, m_, ss_)                                                           \
    do {                                                                               \
        _Pragma("unroll")                                                              \
        for (int el_ = 0; el_ < 4; ++el_) {                                            \
            const size_t b_ = ((size_t)(((m_) * 4 + (ss_)) * 8 + eq * 4 + el_)) * 128; \
            dst_[el_ * 2]     = wp[b_];                                                \
            dst_[el_ * 2 + 1] = wp[b_ + 64];                                           \
        }                                                                              \
    } while (0)

// Pack W_linear||W_noise into MFMA B-fragment order (verified rounds 5-22)
__global__ __launch_bounds__(256)
void prep_w(const float* __restrict__ Wl, const float* __restrict__ Wn,
            ushort* __restrict__ wsB)
{
    const int t    = blockIdx.x * 256 + threadIdx.x;
    const int lane = t & 63;
    const int et   = (t >> 6) & 7;
    const int s    = t >> 9;
    const int e    = et * 16 + (lane & 15);
    const int k    = s * 32 + ((lane >> 4) * 8);
    const float* src = (e < EE) ? &Wl[(long)e * DD + k] : &Wn[(long)(e - EE) * DD + k];
    const float4 f0 = *reinterpret_cast<const float4*>(src);
    const float4 f1 = *reinterpret_cast<const float4*>(src + 4);
    const float f[8] = {f0.x, f0.y, f0.z, f0.w, f1.x, f1.y, f1.z, f1.w};
    uint hw[4], lw[4];
#pragma unroll
    for (int j = 0; j < 4; ++j) {
        ushort h0, l0, h1, l1;
        split_bf16(f[2 * j], h0, l0);
        split_bf16(f[2 * j + 1], h1, l1);
        hw[j] = (uint)h0 | ((uint)h1 << 16);
        lw[j] = (uint)l0 | ((uint)l1 << 16);
    }
    const size_t chunk = ((size_t)(s * 8 + et)) * 1024;
    *reinterpret_cast<uint4*>(&wsB[chunk + lane * 8])       = make_uint4(hw[0], hw[1], hw[2], hw[3]);
    *reinterpret_cast<uint4*>(&wsB[chunk + 512 + lane * 8]) = make_uint4(lw[0], lw[1], lw[2], lw[3]);
}

__global__ __launch_bounds__(NTH, 2)
void router_main(const float* __restrict__ x,
                 const float* __restrict__ noise,
                 const ushort* __restrict__ wsB,
                 const float* __restrict__ Wl, const float* __restrict__ bl,
                 const float* __restrict__ Wn, const float* __restrict__ bn,
                 float* __restrict__ out_router, float* __restrict__ out_idx)
{
    // [0,32K) xbuf0 | [32K,64K) xbuf1 ; post-loop res[64][129] aliases; x-row restage at [0,8K)
    __shared__ __align__(16) unsigned char smem[2 * XB];
    __shared__ float  tkv[TPB][KK];
    __shared__ int    tki[TPB][KK];
    __shared__ int    cand[TPB][10];
    __shared__ int    amb_list[TPB];
    __shared__ int    amb_count;
    __shared__ double dsh[20];

    const int tid  = threadIdx.x;
    const int lane = tid & 63;
    const int w    = tid >> 6;
    const int mh   = w >> 1;
    const int eq   = w & 1;
    const long tok0 = (long)blockIdx.x * TPB;
    if (tid == 0) amb_count = 0;

    const uint4* wp = reinterpret_cast<const uint4*>(wsB) + lane;

    f32x4 acc[2][4];
#pragma unroll
    for (int mt = 0; mt < 2; ++mt)
#pragma unroll
        for (int e = 0; e < 4; ++e) acc[mt][e] = {0.f, 0.f, 0.f, 0.f};

    float4 xr[8];
    uint4 W0[8], W1[8], W2[8], W3[8];

    // prologue: x(0) -> regs -> LDS buf0; W(0, ss0/ss1) preloaded
    XLOAD(0);
    LOADW(W0, 0, 0);
    LOADW(W1, 0, 1);
    XSTORE(0);
    __syncthreads();

    const int colr = lane & 15;
    const int krow = lane >> 4;

    for (int m = 0; m < NMEGA; ++m) {
        const int cur = m & 1;
        if (m + 1 < NMEGA) XLOAD(m + 1);     // issue next-mega x loads (regs, post-barrier)
        const unsigned char* xb = smem + cur * XB;
#pragma unroll
        for (int ss = 0; ss < 4; ++ss) {
            if (ss == 0)      LOADW(W2, m, 2);
            else if (ss == 1) LOADW(W3, m, 3);
            else if (ss == 2) { if (m + 1 < NMEGA) LOADW(W0, m + 1, 0); }
            else              { if (m + 1 < NMEGA) LOADW(W1, m + 1, 1); }

            short8 ah[2], al[2];
#pragma unroll
            for (int mt = 0; mt < 2; ++mt) {
                const int r = mh * 32 + mt * 16 + colr;
                const unsigned char* base = xb + r * 512;
                const int v0 = ss * 8 + krow * 2;
                const float4 f0 = *reinterpret_cast<const float4*>(base + ((v0 ^ (r & 7)) << 4));
                const float4 f1 = *reinterpret_cast<const float4*>(base + (((v0 + 1) ^ (r & 7)) << 4));
                conv_tile(f0, f1, ah[mt], al[mt]);
            }
            const uint4* Wc = (ss == 0) ? W0 : (ss == 1) ? W1 : (ss == 2) ? W2 : W3;
#pragma unroll
            for (int el = 0; el < 4; ++el) {
                const short8 bh  = __builtin_bit_cast(short8, Wc[el * 2]);
                const short8 bl2 = __builtin_bit_cast(short8, Wc[el * 2 + 1]);
                acc[0][el] = __builtin_amdgcn_mfma_f32_16x16x32_bf16(ah[0], bh,  acc[0][el], 0, 0, 0);
                acc[1][el] = __builtin_amdgcn_mfma_f32_16x16x32_bf16(ah[1], bh,  acc[1][el], 0, 0, 0);
                acc[0][el] = __builtin_amdgcn_mfma_f32_16x16x32_bf16(al[0], bh,  acc[0][el], 0, 0, 0);
                acc[1][el] = __builtin_amdgcn_mfma_f32_16x16x32_bf16(al[1], bh,  acc[1][el], 0, 0, 0);
                acc[0][el] = __builtin_amdgcn_mfma_f32_16x16x32_bf16(ah[0], bl2, acc[0][el], 0, 0, 0);
                acc[1][el] = __builtin_amdgcn_mfma_f32_16x16x32_bf16(ah[1], bl2, acc[1][el], 0, 0, 0);
            }
        }
        if (m + 1 < NMEGA) XSTORE(cur ^ 1);  // write next tile (waits regs; latency covered)
        __syncthreads();
    }

    // ---------------- epilogue (res aliases dead stage buffers) ----------------
    float* res = reinterpret_cast<float*>(smem);   // [64][129]
    {
        // C/D layout (verified r5): col = lane&15 (expert), row = (lane>>4)*4 + reg
        const int rg = (lane >> 4) * 4;
#pragma unroll
        for (int mt = 0; mt < 2; ++mt)
#pragma unroll
            for (int el = 0; el < 4; ++el) {
                const int e = (eq * 4 + el) * 16 + colr;
                const float bias = (e < EE) ? bl[e] : bn[e - EE];
#pragma unroll
                for (int r = 0; r < 4; ++r)
                    RES(mh * 32 + mt * 16 + rg + r, e) = acc[mt][el][r] + bias;
            }
    }
    __syncthreads();

    // noisy = logits + noise * softplus(noise_logits); quad per token (same map as scan)
    {
        const int t  = tid >> 2;
        const int e0 = (tid & 3) * 16;
        const float* nrow = &noise[(tok0 + t) * (long)EE];
#pragma unroll 4
        for (int j = 0; j < 16; ++j) {
            const int e = e0 + j;
            const float z  = RES(t, EE + e);
            const float sp = fmaxf(z, 0.f) + log1pf(expf(-fabsf(z)));
            RES(t, e) = RES(t, e) + nrow[e] * sp;
        }
    }
    __syncthreads();

    // top-10 extraction: 4 lanes per token (wave-synchronous); strict > keeps lowest idx
    {
        const int t   = tid >> 2;
        const int sub = tid & 3;
        float lv[10]; int li[10];
#pragma unroll
        for (int k = 0; k < 10; ++k) {
            float best = -INFINITY;
            int bi = sub * 16;
#pragma unroll
            for (int j = 0; j < 16; ++j) {
                const int e = sub * 16 + j;
                const float v = RES(t, e);
                if (v > best) { best = v; bi = e; }
            }
#pragma unroll
            for (int m = 1; m < 4; m <<= 1) {
                const float ov = __shfl_xor(best, m, 64);
                const int   oi = __shfl_xor(bi, m, 64);
                if (ov > best || (ov == best && oi < bi)) { best = ov; bi = oi; }
            }
            lv[k] = best; li[k] = bi;
            if ((bi >> 4) == sub) RES(t, bi) = -INFINITY;   // owner knocks it out
        }
        bool amb = false;
#pragma unroll
        for (int k = 0; k < 9; ++k) amb |= (lv[k] - lv[k + 1] < TAU);
        const float mmax = lv[0];
        float p[KK];
        float sm = 0.f;
#pragma unroll
        for (int k = 0; k < KK; ++k) { p[k] = expf(lv[k] - mmax); sm += p[k]; }
        const float inv = 1.f / sm;
        if (sub == 0) {
#pragma unroll
            for (int k = 0; k < KK; ++k) { tkv[t][k] = p[k] * inv; tki[t][k] = li[k]; }
            if (amb) {
                const int pos = atomicAdd(&amb_count, 1);
                amb_list[pos] = t;
#pragma unroll
                for (int c = 0; c < 10; ++c) cand[t][c] = li[c];
            }
        }
    }
    __syncthreads();

    // fp64 recompute of flagged tokens, RESTRICTED to the fp32 top-10 candidates.
    const int namb = amb_count;
    for (int a = 0; a < namb; ++a) {
        const int t = amb_list[a];
        {   // stage x row (8 KB) into smem[0..8K) — res rows 0..15 are dead
            const float4* xsrc = reinterpret_cast<const float4*>(&x[(tok0 + t) * (long)DD]);
            float4* xd = reinterpret_cast<float4*>(smem);
            xd[tid * 2]     = xsrc[tid * 2];
            xd[tid * 2 + 1] = xsrc[tid * 2 + 1];
        }
        __syncthreads();
        {   // 20 dots (10 experts x {Wl,Wn}), 8 lane-contiguous threads each
            const int g  = tid >> 3;
            const int gs = tid & 7;
            double dsum = 0.0;
            if (g < 20) {
                const int c = (g < 10) ? g : g - 10;
                const int e = cand[t][c];
                const float* wr = (g < 10) ? &Wl[(long)e * DD] : &Wn[(long)e * DD];
                const float* xs = reinterpret_cast<const float*>(smem);
                for (int k = gs * 4; k < DD; k += 32) {
                    const float4 xv = *reinterpret_cast<const float4*>(&xs[k]);
                    const float4 wv = *reinterpret_cast<const float4*>(&wr[k]);
                    dsum = fma((double)xv.x, (double)wv.x, dsum);
                    dsum = fma((double)xv.y, (double)wv.y, dsum);
                    dsum = fma((double)xv.z, (double)wv.z, dsum);
                    dsum = fma((double)xv.w, (double)wv.w, dsum);
                }
            }
#pragma unroll
            for (int m = 1; m < 8; m <<= 1) dsum += __shfl_xor(dsum, m, 64);
            if (g < 20 && (tid & 7) == 0) dsh[g] = dsum;
        }
        __syncthreads();
        if (tid < 64) {   // wave 0: fp64 noisy on 10 lanes + butterfly top-8 + softmax
            double val; int idx;
            if (tid < 10) {
                const int e = cand[t][tid];
                const double v  = dsh[tid] + (double)bl[e];
                const double z  = dsh[10 + tid] + (double)bn[e];
                const double sp = fmax(z, 0.0) + log1p(exp(-fabs(z)));
                val = v + (double)noise[(tok0 + t) * (long)EE + e] * sp;
                idx = e;
            } else { val = -INFINITY; idx = 64 + tid; }
            double sel[KK]; int sidx[KK];
#pragma unroll
            for (int k = 0; k < KK; ++k) {
                double mv = val; int mi = idx;
#pragma unroll
                for (int m = 1; m < 64; m <<= 1) {
                    const double ov = __shfl_xor(mv, m, 64);
                    const int   oi = __shfl_xor(mi, m, 64);
                    if (ov > mv || (ov == mv && oi < mi)) { mv = ov; mi = oi; }
                }
                sel[k] = mv; sidx[k] = mi;
                if (idx == mi) val = -INFINITY;
            }
            if (tid == 0) {
                const double mx = sel[0];
                double p[KK]; double sm = 0.0;
#pragma unroll
                for (int k = 0; k < KK; ++k) { p[k] = exp(sel[k] - mx); sm += p[k]; }
                const double inv = 1.0 / sm;
#pragma unroll
                for (int k = 0; k < KK; ++k) {
                    tkv[t][k] = (float)(p[k] * inv);
                    tki[t][k] = sidx[k];
                }
            }
        }
        __syncthreads();
    }

    // router output: compare-select scatter, coalesced float4 stores
    {
        const int t  = tid >> 2;
        const int e0 = (tid & 3) * 16;
        int   ki[KK];
        float kv[KK];
#pragma unroll
        for (int k = 0; k < KK; ++k) { ki[k] = tki[t][k]; kv[k] = tkv[t][k]; }
        float4 v[4];
        float* vf = reinterpret_cast<float*>(v);
#pragma unroll
        for (int j = 0; j < 16; ++j) {
            float val = 0.f;
#pragma unroll
            for (int k = 0; k < KK; ++k)
                val = (ki[k] == e0 + j) ? kv[k] : val;
            vf[j] = val;
        }
        float4* dst = reinterpret_cast<float4*>(&out_router[(tok0 + t) * (long)EE + e0]);
#pragma unroll
        for (int q = 0; q < 4; ++q) dst[q] = v[q];
    }
    // indices output, written as float32 values (whole d_out read as f32 by harness)
    {
        const int f = tid * 2;
        const int t = f >> 3;
        const int k0i = f & 7;
        out_idx[(tok0 + t) * (long)KK + k0i]     = (float)tki[t][k0i];
        out_idx[(tok0 + t) * (long)KK + k0i + 1] = (float)tki[t][k0i + 1];
    }
}

extern "C" void kernel_launch(void* const* d_in, const int* in_sizes, int n_in,
                              void* d_out, int out_size, void* d_ws, size_t ws_size,
                              hipStream_t stream) {
    const float* x     = (const float*)d_in[0];
    const float* noise = (const float*)d_in[1];
    const float* Wl    = (const float*)d_in[2];
    const float* bl    = (const float*)d_in[3];
    const float* Wn    = (const float*)d_in[4];
    const float* bn    = (const float*)d_in[5];

    const int M = in_sizes[0] / DD;            // B*S = 32768
    float* out_router = (float*)d_out;
    float* out_idx    = (float*)d_out + (long)M * EE;
    ushort* wsB = (ushort*)d_ws;               // 1 MiB fragment-packed W hi/lo

    hipLaunchKernelGGL(prep_w, dim3(128), dim3(256), 0, stream, Wl, Wn, wsB);
    hipLaunchKernelGGL(router_main, dim3(M / TPB), dim3(NTH), 0, stream,
                       x, noise, wsB, Wl, bl, Wn, bn, out_router, out_idx);
}

// Round 24
// 160.610 us; speedup vs baseline: 1.4124x; 1.4124x over previous
//
#include <hip/hip_runtime.h>
#include <hip/hip_bf16.h>
#include <math.h>

namespace {
constexpr int DD = 2048;          // feature dim
constexpr int EE = 64;            // experts
constexpr int KK = 8;             // top-k
constexpr int TPB = 64;           // tokens per block
constexpr int MS = 128;           // K per mega-step
constexpr int NMEGA = DD / MS;    // 16
constexpr int NTH = 256;          // 4 waves
constexpr int XB = TPB * MS * 4;  // 32768 B per x stage buffer (f32)
constexpr float TAU = 2e-4f;      // ambiguity gap threshold (~30 sigma of split-bf16 error)
}

typedef __attribute__((ext_vector_type(8))) short short8;   // 8 bf16 (4 VGPRs)
typedef __attribute__((ext_vector_type(4))) float f32x4;

#define RES(t, e) res[(t) * 129 + (e)]

__device__ inline void split_bf16(float v, ushort& h, ushort& l) {
    __hip_bfloat16 hb = __float2bfloat16(v);
    float hf = __bfloat162float(hb);
    __hip_bfloat16 lb = __float2bfloat16(v - hf);
    h = __builtin_bit_cast(ushort, hb);
    l = __builtin_bit_cast(ushort, lb);
}

__device__ inline void conv_tile(const float4& A, const float4& B, short8& hi, short8& lo) {
    const float f[8] = {A.x, A.y, A.z, A.w, B.x, B.y, B.z, B.w};
#pragma unroll
    for (int i = 0; i < 8; ++i) {
        ushort h, l;
        split_bf16(f[i], h, l);
        hi[i] = (short)h;
        lo[i] = (short)l;
    }
}

__device__ inline void gload_lds16(const void* g, void* l) {
    __builtin_amdgcn_global_load_lds(
        (const __attribute__((address_space(1))) unsigned int*)g,
        (__attribute__((address_space(3))) unsigned int*)l,
        16, 0, 0);
}

// x staging: 8 gload_lds per thread into buffer c_ (dest linear, source swizzled)
#define STAGE(m_, c_)                                                                  \
    do {                                                                               \
        unsigned char* xb_ = smem + (c_) * XB;                                         \
        _Pragma("unroll")                                                              \
        for (int j = 0; j < 8; ++j) {                                                  \
            const int row_ = (w * 8 + j) * 2 + (lane >> 5);                            \
            const int u_   = lane & 31;                                                \
            const float* g_ = x + (tok0 + row_) * (long)DD + (long)(m_) * MS           \
                              + ((u_ ^ (row_ & 7)) << 2);                              \
            gload_lds16(g_, xb_ + (w * 8 + j) * 1024);                                 \
        }                                                                              \
    } while (0)

// W fragment load for (mega m, substep ss) into 8 uint4 (4 et x hi/lo)
#define LOADW(dst_, m_, ss_)                                                           \
    do {                                                                               \
        _Pragma("unroll")                                                              \
        for (int el_ = 0; el_ < 4; ++el_) {                                            \
            const size_t b_ = ((size_t)(((m_) * 4 + (ss_)) * 8 + eq * 4 + el_)) * 128; \
            dst_[el_ * 2]     = wp[b_];                                                \
            dst_[el_ * 2 + 1] = wp[b_ + 64];                                           \
        }                                                                              \
    } while (0)

// Pack W_linear||W_noise into MFMA B-fragment order (verified rounds 5-22)
__global__ __launch_bounds__(256)
void prep_w(const float* __restrict__ Wl, const float* __restrict__ Wn,
            ushort* __restrict__ wsB)
{
    const int t    = blockIdx.x * 256 + threadIdx.x;
    const int lane = t & 63;
    const int et   = (t >> 6) & 7;
    const int s    = t >> 9;
    const int e    = et * 16 + (lane & 15);
    const int k    = s * 32 + ((lane >> 4) * 8);
    const float* src = (e < EE) ? &Wl[(long)e * DD + k] : &Wn[(long)(e - EE) * DD + k];
    const float4 f0 = *reinterpret_cast<const float4*>(src);
    const float4 f1 = *reinterpret_cast<const float4*>(src + 4);
    const float f[8] = {f0.x, f0.y, f0.z, f0.w, f1.x, f1.y, f1.z, f1.w};
    uint hw[4], lw[4];
#pragma unroll
    for (int j = 0; j < 4; ++j) {
        ushort h0, l0, h1, l1;
        split_bf16(f[2 * j], h0, l0);
        split_bf16(f[2 * j + 1], h1, l1);
        hw[j] = (uint)h0 | ((uint)h1 << 16);
        lw[j] = (uint)l0 | ((uint)l1 << 16);
    }
    const size_t chunk = ((size_t)(s * 8 + et)) * 1024;
    *reinterpret_cast<uint4*>(&wsB[chunk + lane * 8])       = make_uint4(hw[0], hw[1], hw[2], hw[3]);
    *reinterpret_cast<uint4*>(&wsB[chunk + 512 + lane * 8]) = make_uint4(lw[0], lw[1], lw[2], lw[3]);
}

__global__ __launch_bounds__(NTH, 2)
void router_main(const float* __restrict__ x,
                 const float* __restrict__ noise,
                 const ushort* __restrict__ wsB,
                 const float* __restrict__ Wl, const float* __restrict__ bl,
                 const float* __restrict__ Wn, const float* __restrict__ bn,
                 float* __restrict__ out_router, float* __restrict__ out_idx)
{
    // [0,32K) xbuf0 | [32K,64K) xbuf1 ; post-loop res[64][129] aliases; x-row restage at [0,8K)
    __shared__ __align__(16) unsigned char smem[2 * XB];
    __shared__ float  tkv[TPB][KK];
    __shared__ int    tki[TPB][KK];
    __shared__ int    cand[TPB][10];
    __shared__ int    amb_list[TPB];
    __shared__ int    amb_count;
    __shared__ double dsh[20];

    const int tid  = threadIdx.x;
    const int lane = tid & 63;
    const int w    = tid >> 6;
    const int mh   = w >> 1;
    const int eq   = w & 1;
    const long tok0 = (long)blockIdx.x * TPB;
    if (tid == 0) amb_count = 0;

    const uint4* wp = reinterpret_cast<const uint4*>(wsB) + lane;

    f32x4 acc[2][4];
#pragma unroll
    for (int mt = 0; mt < 2; ++mt)
#pragma unroll
        for (int e = 0; e < 4; ++e) acc[mt][e] = {0.f, 0.f, 0.f, 0.f};

    uint4 W0[8], W1[8], W2[8], W3[8];
    STAGE(0, 0);
    LOADW(W0, 0, 0);
    LOADW(W1, 0, 1);
    __syncthreads();

    const int colr = lane & 15;
    const int krow = lane >> 4;

    for (int m = 0; m < NMEGA; ++m) {
        const int cur = m & 1;
        if (m + 1 < NMEGA) STAGE(m + 1, cur ^ 1);
        const unsigned char* xb = smem + cur * XB;
#pragma unroll
        for (int ss = 0; ss < 4; ++ss) {
            if (ss == 0)      LOADW(W2, m, 2);
            else if (ss == 1) LOADW(W3, m, 3);
            else if (ss == 2) { if (m + 1 < NMEGA) LOADW(W0, m + 1, 0); }
            else              { if (m + 1 < NMEGA) LOADW(W1, m + 1, 1); }

            short8 ah[2], al[2];
#pragma unroll
            for (int mt = 0; mt < 2; ++mt) {
                const int r = mh * 32 + mt * 16 + colr;
                const unsigned char* base = xb + r * 512;
                const int v0 = ss * 8 + krow * 2;
                const float4 f0 = *reinterpret_cast<const float4*>(base + ((v0 ^ (r & 7)) << 4));
                const float4 f1 = *reinterpret_cast<const float4*>(base + (((v0 + 1) ^ (r & 7)) << 4));
                conv_tile(f0, f1, ah[mt], al[mt]);
            }
            const uint4* Wc = (ss == 0) ? W0 : (ss == 1) ? W1 : (ss == 2) ? W2 : W3;
#pragma unroll
            for (int el = 0; el < 4; ++el) {
                const short8 bh  = __builtin_bit_cast(short8, Wc[el * 2]);
                const short8 bl2 = __builtin_bit_cast(short8, Wc[el * 2 + 1]);
                acc[0][el] = __builtin_amdgcn_mfma_f32_16x16x32_bf16(ah[0], bh,  acc[0][el], 0, 0, 0);
                acc[1][el] = __builtin_amdgcn_mfma_f32_16x16x32_bf16(ah[1], bh,  acc[1][el], 0, 0, 0);
                acc[0][el] = __builtin_amdgcn_mfma_f32_16x16x32_bf16(al[0], bh,  acc[0][el], 0, 0, 0);
                acc[1][el] = __builtin_amdgcn_mfma_f32_16x16x32_bf16(al[1], bh,  acc[1][el], 0, 0, 0);
                acc[0][el] = __builtin_amdgcn_mfma_f32_16x16x32_bf16(ah[0], bl2, acc[0][el], 0, 0, 0);
                acc[1][el] = __builtin_amdgcn_mfma_f32_16x16x32_bf16(ah[1], bl2, acc[1][el], 0, 0, 0);
            }
        }
        __syncthreads();
    }

    // ---------------- epilogue (res aliases dead stage buffers) ----------------
    float* res = reinterpret_cast<float*>(smem);   // [64][129]
    {
        // C/D layout (verified r5): col = lane&15 (expert), row = (lane>>4)*4 + reg
        const int rg = (lane >> 4) * 4;
#pragma unroll
        for (int mt = 0; mt < 2; ++mt)
#pragma unroll
            for (int el = 0; el < 4; ++el) {
                const int e = (eq * 4 + el) * 16 + colr;
                const float bias = (e < EE) ? bl[e] : bn[e - EE];
#pragma unroll
                for (int r = 0; r < 4; ++r)
                    RES(mh * 32 + mt * 16 + rg + r, e) = acc[mt][el][r] + bias;
            }
    }
    __syncthreads();

    // noisy = logits + noise * softplus(noise_logits); quad per token (same map as scan)
    {
        const int t  = tid >> 2;
        const int e0 = (tid & 3) * 16;
        const float* nrow = &noise[(tok0 + t) * (long)EE];
#pragma unroll 4
        for (int j = 0; j < 16; ++j) {
            const int e = e0 + j;
            const float z  = RES(t, EE + e);
            const float sp = fmaxf(z, 0.f) + log1pf(expf(-fabsf(z)));
            RES(t, e) = RES(t, e) + nrow[e] * sp;
        }
    }
    __syncthreads();

    // top-10 extraction: 4 lanes per token (wave-synchronous); strict > keeps lowest idx
    {
        const int t   = tid >> 2;
        const int sub = tid & 3;
        float lv[10]; int li[10];
#pragma unroll
        for (int k = 0; k < 10; ++k) {
            float best = -INFINITY;
            int bi = sub * 16;
#pragma unroll
            for (int j = 0; j < 16; ++j) {
                const int e = sub * 16 + j;
                const float v = RES(t, e);
                if (v > best) { best = v; bi = e; }
            }
#pragma unroll
            for (int m = 1; m < 4; m <<= 1) {
                const float ov = __shfl_xor(best, m, 64);
                const int   oi = __shfl_xor(bi, m, 64);
                if (ov > best || (ov == best && oi < bi)) { best = ov; bi = oi; }
            }
            lv[k] = best; li[k] = bi;
            if ((bi >> 4) == sub) RES(t, bi) = -INFINITY;   // owner knocks it out
        }
        bool amb = false;
#pragma unroll
        for (int k = 0; k < 9; ++k) amb |= (lv[k] - lv[k + 1] < TAU);
        const float mmax = lv[0];
        float p[KK];
        float sm = 0.f;
#pragma unroll
        for (int k = 0; k < KK; ++k) { p[k] = expf(lv[k] - mmax); sm += p[k]; }
        const float inv = 1.f / sm;
        if (sub == 0) {
#pragma unroll
            for (int k = 0; k < KK; ++k) { tkv[t][k] = p[k] * inv; tki[t][k] = li[k]; }
            if (amb) {
                const int pos = atomicAdd(&amb_count, 1);
                amb_list[pos] = t;
#pragma unroll
                for (int c = 0; c < 10; ++c) cand[t][c] = li[c];
            }
        }
    }
    __syncthreads();

    // fp64 recompute of flagged tokens, RESTRICTED to the fp32 top-10 candidates.
    // Only they can contest the output top-8 (gap >= TAU below is > 30 sigma safe).
    const int namb = amb_count;
    for (int a = 0; a < namb; ++a) {
        const int t = amb_list[a];
        {   // stage x row (8 KB) into smem[0..8K) — res rows 0..15 are dead
            const float4* xsrc = reinterpret_cast<const float4*>(&x[(tok0 + t) * (long)DD]);
            float4* xd = reinterpret_cast<float4*>(smem);
            xd[tid * 2]     = xsrc[tid * 2];
            xd[tid * 2 + 1] = xsrc[tid * 2 + 1];
        }
        __syncthreads();
        {   // 20 dots (10 experts x {Wl,Wn}), 8 lane-contiguous threads each
            const int g  = tid >> 3;
            const int gs = tid & 7;
            double dsum = 0.0;
            if (g < 20) {
                const int c = (g < 10) ? g : g - 10;
                const int e = cand[t][c];
                const float* wr = (g < 10) ? &Wl[(long)e * DD] : &Wn[(long)e * DD];
                const float* xs = reinterpret_cast<const float*>(smem);
                for (int k = gs * 4; k < DD; k += 32) {
                    const float4 xv = *reinterpret_cast<const float4*>(&xs[k]);
                    const float4 wv = *reinterpret_cast<const float4*>(&wr[k]);
                    dsum = fma((double)xv.x, (double)wv.x, dsum);
                    dsum = fma((double)xv.y, (double)wv.y, dsum);
                    dsum = fma((double)xv.z, (double)wv.z, dsum);
                    dsum = fma((double)xv.w, (double)wv.w, dsum);
                }
            }
#pragma unroll
            for (int m = 1; m < 8; m <<= 1) dsum += __shfl_xor(dsum, m, 64);
            if (g < 20 && (tid & 7) == 0) dsh[g] = dsum;
        }
        __syncthreads();
        if (tid < 64) {   // wave 0: fp64 noisy on 10 lanes + butterfly top-8 + softmax
            double val; int idx;
            if (tid < 10) {
                const int e = cand[t][tid];
                const double v  = dsh[tid] + (double)bl[e];
                const double z  = dsh[10 + tid] + (double)bn[e];
                const double sp = fmax(z, 0.0) + log1p(exp(-fabs(z)));
                val = v + (double)noise[(tok0 + t) * (long)EE + e] * sp;
                idx = e;
            } else { val = -INFINITY; idx = 64 + tid; }
            double sel[KK]; int sidx[KK];
#pragma unroll
            for (int k = 0; k < KK; ++k) {
                double mv = val; int mi = idx;
#pragma unroll
                for (int m = 1; m < 64; m <<= 1) {
                    const double ov = __shfl_xor(mv, m, 64);
                    const int   oi = __shfl_xor(mi, m, 64);
                    if (ov > mv || (ov == mv && oi < mi)) { mv = ov; mi = oi; }
                }
                sel[k] = mv; sidx[k] = mi;
                if (idx == mi) val = -INFINITY;
            }
            if (tid == 0) {
                const double mx = sel[0];
                double p[KK]; double sm = 0.0;
#pragma unroll
                for (int k = 0; k < KK; ++k) { p[k] = exp(sel[k] - mx); sm += p[k]; }
                const double inv = 1.0 / sm;
#pragma unroll
                for (int k = 0; k < KK; ++k) {
                    tkv[t][k] = (float)(p[k] * inv);
                    tki[t][k] = sidx[k];
                }
            }
        }
        __syncthreads();
    }

    // router output: compare-select scatter, coalesced float4 stores
    {
        const int t  = tid >> 2;
        const int e0 = (tid & 3) * 16;
        int   ki[KK];
        float kv[KK];
#pragma unroll
        for (int k = 0; k < KK; ++k) { ki[k] = tki[t][k]; kv[k] = tkv[t][k]; }
        float4 v[4];
        float* vf = reinterpret_cast<float*>(v);
#pragma unroll
        for (int j = 0; j < 16; ++j) {
            float val = 0.f;
#pragma unroll
            for (int k = 0; k < KK; ++k)
                val = (ki[k] == e0 + j) ? kv[k] : val;
            vf[j] = val;
        }
        float4* dst = reinterpret_cast<float4*>(&out_router[(tok0 + t) * (long)EE + e0]);
#pragma unroll
        for (int q = 0; q < 4; ++q) dst[q] = v[q];
    }
    // indices output, written as float32 values (whole d_out read as f32 by harness)
    {
        const int f = tid * 2;
        const int t = f >> 3;
        const int k0i = f & 7;
        out_idx[(tok0 + t) * (long)KK + k0i]     = (float)tki[t][k0i];
        out_idx[(tok0 + t) * (long)KK + k0i + 1] = (float)tki[t][k0i + 1];
    }
}

extern "C" void kernel_launch(void* const* d_in, const int* in_sizes, int n_in,
                              void* d_out, int out_size, void* d_ws, size_t ws_size,
                              hipStream_t stream) {
    const float* x     = (const float*)d_in[0];
    const float* noise = (const float*)d_in[1];
    const float* Wl    = (const float*)d_in[2];
    const float* bl    = (const float*)d_in[3];
    const float* Wn    = (const float*)d_in[4];
    const float* bn    = (const float*)d_in[5];

    const int M = in_sizes[0] / DD;            // B*S = 32768
    float* out_router = (float*)d_out;
    float* out_idx    = (float*)d_out + (long)M * EE;
    ushort* wsB = (ushort*)d_ws;               // 1 MiB fragment-packed W hi/lo

    hipLaunchKernelGGL(prep_w, dim3(128), dim3(256), 0, stream, Wl, Wn, wsB);
    hipLaunchKernelGGL(router_main, dim3(M / TPB), dim3(NTH), 0, stream,
                       x, noise, wsB, Wl, bl, Wn, bn, out_router, out_idx);
}

// Round 25
// 160.261 us; speedup vs baseline: 1.4155x; 1.0022x over previous
//
#include <hip/hip_runtime.h>
#include <hip/hip_bf16.h>
#include <math.h>

namespace {
constexpr int DD = 2048;          // feature dim
constexpr int EE = 64;            // experts
constexpr int KK = 8;             // top-k
constexpr int TPB = 64;           // tokens per block
constexpr int MS = 128;           // K per mega-step
constexpr int NMEGA = DD / MS;    // 16
constexpr int NTH = 256;          // 4 waves
constexpr int XB = TPB * MS * 4;  // 32768 B per x stage buffer (f32)
constexpr float TAU = 2e-4f;      // ambiguity gap threshold (~30 sigma of split-bf16 error)
}

typedef __attribute__((ext_vector_type(8))) short short8;   // 8 bf16 (4 VGPRs)
typedef __attribute__((ext_vector_type(4))) float f32x4;

#define RES(t, e) res[(t) * 129 + (e)]

__device__ inline void split_bf16(float v, ushort& h, ushort& l) {
    __hip_bfloat16 hb = __float2bfloat16(v);
    float hf = __bfloat162float(hb);
    __hip_bfloat16 lb = __float2bfloat16(v - hf);
    h = __builtin_bit_cast(ushort, hb);
    l = __builtin_bit_cast(ushort, lb);
}

__device__ inline void conv_tile(const float4& A, const float4& B, short8& hi, short8& lo) {
    const float f[8] = {A.x, A.y, A.z, A.w, B.x, B.y, B.z, B.w};
#pragma unroll
    for (int i = 0; i < 8; ++i) {
        ushort h, l;
        split_bf16(f[i], h, l);
        hi[i] = (short)h;
        lo[i] = (short)l;
    }
}

__device__ inline void gload_lds16(const void* g, void* l) {
    __builtin_amdgcn_global_load_lds(
        (const __attribute__((address_space(1))) unsigned int*)g,
        (__attribute__((address_space(3))) unsigned int*)l,
        16, 0, 0);
}

// x staging: 8 gload_lds per thread into buffer c_ (dest linear, source swizzled)
#define STAGE(m_, c_)                                                                  \
    do {                                                                               \
        unsigned char* xb_ = smem + (c_) * XB;                                         \
        _Pragma("unroll")                                                              \
        for (int j = 0; j < 8; ++j) {                                                  \
            const int row_ = (w * 8 + j) * 2 + (lane >> 5);                            \
            const int u_   = lane & 31;                                                \
            const float* g_ = x + (tok0 + row_) * (long)DD + (long)(m_) * MS           \
                              + ((u_ ^ (row_ & 7)) << 2);                              \
            gload_lds16(g_, xb_ + (w * 8 + j) * 1024);                                 \
        }                                                                              \
    } while (0)

// W fragment load for (mega m, substep ss) into 8 uint4 (4 et x hi/lo)
#define LOADW(dst_, m_, ss_)                                                           \
    do {                                                                               \
        _Pragma("unroll")                                                              \
        for (int el_ = 0; el_ < 4; ++el_) {                                            \
            const size_t b_ = ((size_t)(((m_) * 4 + (ss_)) * 8 + eq * 4 + el_)) * 128; \
            dst_[el_ * 2]     = wp[b_];                                                \
            dst_[el_ * 2 + 1] = wp[b_ + 64];                                           \
        }                                                                              \
    } while (0)

// Pack W_linear||W_noise into MFMA B-fragment order (verified rounds 5-24)
__global__ __launch_bounds__(256)
void prep_w(const float* __restrict__ Wl, const float* __restrict__ Wn,
            ushort* __restrict__ wsB)
{
    const int t    = blockIdx.x * 256 + threadIdx.x;
    const int lane = t & 63;
    const int et   = (t >> 6) & 7;
    const int s    = t >> 9;
    const int e    = et * 16 + (lane & 15);
    const int k    = s * 32 + ((lane >> 4) * 8);
    const float* src = (e < EE) ? &Wl[(long)e * DD + k] : &Wn[(long)(e - EE) * DD + k];
    const float4 f0 = *reinterpret_cast<const float4*>(src);
    const float4 f1 = *reinterpret_cast<const float4*>(src + 4);
    const float f[8] = {f0.x, f0.y, f0.z, f0.w, f1.x, f1.y, f1.z, f1.w};
    uint hw[4], lw[4];
#pragma unroll
    for (int j = 0; j < 4; ++j) {
        ushort h0, l0, h1, l1;
        split_bf16(f[2 * j], h0, l0);
        split_bf16(f[2 * j + 1], h1, l1);
        hw[j] = (uint)h0 | ((uint)h1 << 16);
        lw[j] = (uint)l0 | ((uint)l1 << 16);
    }
    const size_t chunk = ((size_t)(s * 8 + et)) * 1024;
    *reinterpret_cast<uint4*>(&wsB[chunk + lane * 8])       = make_uint4(hw[0], hw[1], hw[2], hw[3]);
    *reinterpret_cast<uint4*>(&wsB[chunk + 512 + lane * 8]) = make_uint4(lw[0], lw[1], lw[2], lw[3]);
}

__global__ __launch_bounds__(NTH, 2)
void router_main(const float* __restrict__ x,
                 const float* __restrict__ noise,
                 const ushort* __restrict__ wsB,
                 const float* __restrict__ Wl, const float* __restrict__ bl,
                 const float* __restrict__ Wn, const float* __restrict__ bn,
                 float* __restrict__ out_router, float* __restrict__ out_idx)
{
    // [0,32K) xbuf0 | [32K,64K) xbuf1 ; post-loop res[64][129] aliases; x-row restage at [0,8K)
    __shared__ __align__(16) unsigned char smem[2 * XB];
    __shared__ float  tkv[TPB][KK];
    __shared__ int    tki[TPB][KK];
    __shared__ int    cand[TPB][10];
    __shared__ int    amb_list[TPB];
    __shared__ int    amb_count;
    __shared__ double dsh[20];

    const int tid  = threadIdx.x;
    const int lane = tid & 63;
    const int w    = tid >> 6;
    const int mh   = w >> 1;
    const int eq   = w & 1;
    const long tok0 = (long)blockIdx.x * TPB;
    if (tid == 0) amb_count = 0;

    const uint4* wp = reinterpret_cast<const uint4*>(wsB) + lane;

    f32x4 acc[2][4];
#pragma unroll
    for (int mt = 0; mt < 2; ++mt)
#pragma unroll
        for (int e = 0; e < 4; ++e) acc[mt][e] = {0.f, 0.f, 0.f, 0.f};

    uint4 W0[8], W1[8], W2[8], W3[8];
    STAGE(0, 0);
    LOADW(W0, 0, 0);
    LOADW(W1, 0, 1);
    __syncthreads();

    const int colr = lane & 15;
    const int krow = lane >> 4;

    for (int m = 0; m < NMEGA; ++m) {
        const int cur = m & 1;
        if (m + 1 < NMEGA) STAGE(m + 1, cur ^ 1);
        const unsigned char* xb = smem + cur * XB;
#pragma unroll
        for (int ss = 0; ss < 4; ++ss) {
            if (ss == 0)      LOADW(W2, m, 2);
            else if (ss == 1) LOADW(W3, m, 3);
            else if (ss == 2) { if (m + 1 < NMEGA) LOADW(W0, m + 1, 0); }
            else              { if (m + 1 < NMEGA) LOADW(W1, m + 1, 1); }

            short8 ah[2], al[2];
#pragma unroll
            for (int mt = 0; mt < 2; ++mt) {
                const int r = mh * 32 + mt * 16 + colr;
                const unsigned char* base = xb + r * 512;
                const int v0 = ss * 8 + krow * 2;
                const float4 f0 = *reinterpret_cast<const float4*>(base + ((v0 ^ (r & 7)) << 4));
                const float4 f1 = *reinterpret_cast<const float4*>(base + (((v0 + 1) ^ (r & 7)) << 4));
                conv_tile(f0, f1, ah[mt], al[mt]);
            }
            const uint4* Wc = (ss == 0) ? W0 : (ss == 1) ? W1 : (ss == 2) ? W2 : W3;
#pragma unroll
            for (int el = 0; el < 4; ++el) {
                const short8 bh  = __builtin_bit_cast(short8, Wc[el * 2]);
                const short8 bl2 = __builtin_bit_cast(short8, Wc[el * 2 + 1]);
                acc[0][el] = __builtin_amdgcn_mfma_f32_16x16x32_bf16(ah[0], bh,  acc[0][el], 0, 0, 0);
                acc[1][el] = __builtin_amdgcn_mfma_f32_16x16x32_bf16(ah[1], bh,  acc[1][el], 0, 0, 0);
                acc[0][el] = __builtin_amdgcn_mfma_f32_16x16x32_bf16(al[0], bh,  acc[0][el], 0, 0, 0);
                acc[1][el] = __builtin_amdgcn_mfma_f32_16x16x32_bf16(al[1], bh,  acc[1][el], 0, 0, 0);
                acc[0][el] = __builtin_amdgcn_mfma_f32_16x16x32_bf16(ah[0], bl2, acc[0][el], 0, 0, 0);
                acc[1][el] = __builtin_amdgcn_mfma_f32_16x16x32_bf16(ah[1], bl2, acc[1][el], 0, 0, 0);
            }
        }
        __syncthreads();
    }

    // ---------------- epilogue (res aliases dead stage buffers) ----------------
    float* res = reinterpret_cast<float*>(smem);   // [64][129]
    {
        // C/D layout (verified r5): col = lane&15 (expert), row = (lane>>4)*4 + reg
        const int rg = (lane >> 4) * 4;
#pragma unroll
        for (int mt = 0; mt < 2; ++mt)
#pragma unroll
            for (int el = 0; el < 4; ++el) {
                const int e = (eq * 4 + el) * 16 + colr;
                const float bias = (e < EE) ? bl[e] : bn[e - EE];
#pragma unroll
                for (int r = 0; r < 4; ++r)
                    RES(mh * 32 + mt * 16 + rg + r, e) = acc[mt][el][r] + bias;
            }
    }
    __syncthreads();

    // noisy = logits + noise * softplus(noise_logits); quad per token (same map as scan)
    {
        const int t  = tid >> 2;
        const int e0 = (tid & 3) * 16;
        const float* nrow = &noise[(tok0 + t) * (long)EE];
#pragma unroll 4
        for (int j = 0; j < 16; ++j) {
            const int e = e0 + j;
            const float z  = RES(t, EE + e);
            const float sp = fmaxf(z, 0.f) + log1pf(expf(-fabsf(z)));
            RES(t, e) = RES(t, e) + nrow[e] * sp;
        }
    }
    __syncthreads();

    // top-10 extraction: 4 lanes per token (wave-synchronous); strict > keeps lowest idx
    {
        const int t   = tid >> 2;
        const int sub = tid & 3;
        float lv[10]; int li[10];
#pragma unroll
        for (int k = 0; k < 10; ++k) {
            float best = -INFINITY;
            int bi = sub * 16;
#pragma unroll
            for (int j = 0; j < 16; ++j) {
                const int e = sub * 16 + j;
                const float v = RES(t, e);
                if (v > best) { best = v; bi = e; }
            }
#pragma unroll
            for (int m = 1; m < 4; m <<= 1) {
                const float ov = __shfl_xor(best, m, 64);
                const int   oi = __shfl_xor(bi, m, 64);
                if (ov > best || (ov == best && oi < bi)) { best = ov; bi = oi; }
            }
            lv[k] = best; li[k] = bi;
            if ((bi >> 4) == sub) RES(t, bi) = -INFINITY;   // owner knocks it out
        }
        bool amb = false;
#pragma unroll
        for (int k = 0; k < 9; ++k) amb |= (lv[k] - lv[k + 1] < TAU);
        const float mmax = lv[0];
        float p[KK];
        float sm = 0.f;
#pragma unroll
        for (int k = 0; k < KK; ++k) { p[k] = expf(lv[k] - mmax); sm += p[k]; }
        const float inv = 1.f / sm;
        if (sub == 0) {
#pragma unroll
            for (int k = 0; k < KK; ++k) { tkv[t][k] = p[k] * inv; tki[t][k] = li[k]; }
            if (amb) {
                const int pos = atomicAdd(&amb_count, 1);
                amb_list[pos] = t;
#pragma unroll
                for (int c = 0; c < 10; ++c) cand[t][c] = li[c];
            }
        }
    }
    __syncthreads();

    // fp64 recompute of flagged tokens, RESTRICTED to the fp32 top-10 candidates.
    // Only they can contest the output top-8 (gap >= TAU below is > 30 sigma safe).
    const int namb = amb_count;
    for (int a = 0; a < namb; ++a) {
        const int t = amb_list[a];
        {   // stage x row (8 KB) into smem[0..8K) — res rows 0..15 are dead
            const float4* xsrc = reinterpret_cast<const float4*>(&x[(tok0 + t) * (long)DD]);
            float4* xd = reinterpret_cast<float4*>(smem);
            xd[tid * 2]     = xsrc[tid * 2];
            xd[tid * 2 + 1] = xsrc[tid * 2 + 1];
        }
        __syncthreads();
        {   // 20 dots (10 experts x {Wl,Wn}), 8 lane-contiguous threads each
            const int g  = tid >> 3;
            const int gs = tid & 7;
            double dsum = 0.0;
            if (g < 20) {
                const int c = (g < 10) ? g : g - 10;
                const int e = cand[t][c];
                const float* wr = (g < 10) ? &Wl[(long)e * DD] : &Wn[(long)e * DD];
                const float* xs = reinterpret_cast<const float*>(smem);
                for (int k = gs * 4; k < DD; k += 32) {
                    const float4 xv = *reinterpret_cast<const float4*>(&xs[k]);
                    const float4 wv = *reinterpret_cast<const float4*>(&wr[k]);
                    dsum = fma((double)xv.x, (double)wv.x, dsum);
                    dsum = fma((double)xv.y, (double)wv.y, dsum);
                    dsum = fma((double)xv.z, (double)wv.z, dsum);
                    dsum = fma((double)xv.w, (double)wv.w, dsum);
                }
            }
#pragma unroll
            for (int m = 1; m < 8; m <<= 1) dsum += __shfl_xor(dsum, m, 64);
            if (g < 20 && (tid & 7) == 0) dsh[g] = dsum;
        }
        __syncthreads();
        if (tid < 64) {   // wave 0: fp64 noisy on 10 lanes + butterfly top-8 + softmax
            double val; int idx;
            if (tid < 10) {
                const int e = cand[t][tid];
                const double v  = dsh[tid] + (double)bl[e];
                const double z  = dsh[10 + tid] + (double)bn[e];
                const double sp = fmax(z, 0.0) + log1p(exp(-fabs(z)));
                val = v + (double)noise[(tok0 + t) * (long)EE + e] * sp;
                idx = e;
            } else { val = -INFINITY; idx = 64 + tid; }
            double sel[KK]; int sidx[KK];
#pragma unroll
            for (int k = 0; k < KK; ++k) {
                double mv = val; int mi = idx;
#pragma unroll
                for (int m = 1; m < 64; m <<= 1) {
                    const double ov = __shfl_xor(mv, m, 64);
                    const int   oi = __shfl_xor(mi, m, 64);
                    if (ov > mv || (ov == mv && oi < mi)) { mv = ov; mi = oi; }
                }
                sel[k] = mv; sidx[k] = mi;
                if (idx == mi) val = -INFINITY;
            }
            if (tid == 0) {
                const double mx = sel[0];
                double p[KK]; double sm = 0.0;
#pragma unroll
                for (int k = 0; k < KK; ++k) { p[k] = exp(sel[k] - mx); sm += p[k]; }
                const double inv = 1.0 / sm;
#pragma unroll
                for (int k = 0; k < KK; ++k) {
                    tkv[t][k] = (float)(p[k] * inv);
                    tki[t][k] = sidx[k];
                }
            }
        }
        __syncthreads();
    }

    // router output: compare-select scatter, coalesced float4 stores
    {
        const int t  = tid >> 2;
        const int e0 = (tid & 3) * 16;
        int   ki[KK];
        float kv[KK];
#pragma unroll
        for (int k = 0; k < KK; ++k) { ki[k] = tki[t][k]; kv[k] = tkv[t][k]; }
        float4 v[4];
        float* vf = reinterpret_cast<float*>(v);
#pragma unroll
        for (int j = 0; j < 16; ++j) {
            float val = 0.f;
#pragma unroll
            for (int k = 0; k < KK; ++k)
                val = (ki[k] == e0 + j) ? kv[k] : val;
            vf[j] = val;
        }
        float4* dst = reinterpret_cast<float4*>(&out_router[(tok0 + t) * (long)EE + e0]);
#pragma unroll
        for (int q = 0; q < 4; ++q) dst[q] = v[q];
    }
    // indices output, written as float32 values (whole d_out read as f32 by harness)
    {
        const int f = tid * 2;
        const int t = f >> 3;
        const int k0i = f & 7;
        out_idx[(tok0 + t) * (long)KK + k0i]     = (float)tki[t][k0i];
        out_idx[(tok0 + t) * (long)KK + k0i + 1] = (float)tki[t][k0i + 1];
    }
}

extern "C" void kernel_launch(void* const* d_in, const int* in_sizes, int n_in,
                              void* d_out, int out_size, void* d_ws, size_t ws_size,
                              hipStream_t stream) {
    const float* x     = (const float*)d_in[0];
    const float* noise = (const float*)d_in[1];
    const float* Wl    = (const float*)d_in[2];
    const float* bl    = (const float*)d_in[3];
    const float* Wn    = (const float*)d_in[4];
    const float* bn    = (const float*)d_in[5];

    const int M = in_sizes[0] / DD;            // B*S = 32768
    float* out_router = (float*)d_out;
    float* out_idx    = (float*)d_out + (long)M * EE;
    ushort* wsB = (ushort*)d_ws;               // 1 MiB fragment-packed W hi/lo

    hipLaunchKernelGGL(prep_w, dim3(128), dim3(256), 0, stream, Wl, Wn, wsB);
    hipLaunchKernelGGL(router_main, dim3(M / TPB), dim3(NTH), 0, stream,
                       x, noise, wsB, Wl, bl, Wn, bn, out_router, out_idx);
}

// Round 26
// 159.569 us; speedup vs baseline: 1.4216x; 1.0043x over previous
//
#include <hip/hip_runtime.h>
#include <hip/hip_bf16.h>
#include <math.h>

namespace {
constexpr int DD = 2048;          // feature dim
constexpr int EE = 64;            // experts
constexpr int KK = 8;             // top-k
constexpr int TPB = 64;           // tokens per block
constexpr int MS = 128;           // K per mega-step
constexpr int NMEGA = DD / MS;    // 16
constexpr int NTH = 256;          // 4 waves
constexpr int XB = TPB * MS * 4;  // 32768 B per x stage buffer (f32)
constexpr float TAU = 2e-4f;      // ambiguity gap threshold (~30 sigma of split-bf16 error)
}

typedef __attribute__((ext_vector_type(8))) short short8;   // 8 bf16 (4 VGPRs)
typedef __attribute__((ext_vector_type(4))) float f32x4;

#define RES(t, e) res[(t) * 129 + (e)]

__device__ inline void split_bf16(float v, ushort& h, ushort& l) {
    __hip_bfloat16 hb = __float2bfloat16(v);
    float hf = __bfloat162float(hb);
    __hip_bfloat16 lb = __float2bfloat16(v - hf);
    h = __builtin_bit_cast(ushort, hb);
    l = __builtin_bit_cast(ushort, lb);
}

__device__ inline void conv_tile(const float4& A, const float4& B, short8& hi, short8& lo) {
    const float f[8] = {A.x, A.y, A.z, A.w, B.x, B.y, B.z, B.w};
#pragma unroll
    for (int i = 0; i < 8; ++i) {
        ushort h, l;
        split_bf16(f[i], h, l);
        hi[i] = (short)h;
        lo[i] = (short)l;
    }
}

__device__ inline void gload_lds16(const void* g, void* l) {
    __builtin_amdgcn_global_load_lds(
        (const __attribute__((address_space(1))) unsigned int*)g,
        (__attribute__((address_space(3))) unsigned int*)l,
        16, 0, 0);
}

// x staging: 8 gload_lds per thread into buffer c_ (dest linear, source swizzled)
#define STAGE(m_, c_)                                                                  \
    do {                                                                               \
        unsigned char* xb_ = smem + (c_) * XB;                                         \
        _Pragma("unroll")                                                              \
        for (int j = 0; j < 8; ++j) {                                                  \
            const int row_ = (w * 8 + j) * 2 + (lane >> 5);                            \
            const int u_   = lane & 31;                                                \
            const float* g_ = x + (tok0 + row_) * (long)DD + (long)(m_) * MS           \
                              + ((u_ ^ (row_ & 7)) << 2);                              \
            gload_lds16(g_, xb_ + (w * 8 + j) * 1024);                                 \
        }                                                                              \
    } while (0)

// W fragment load for (mega m, substep ss) into 8 uint4 (4 et x hi/lo)
#define LOADW(dst_, m_, ss_)                                                           \
    do {                                                                               \
        _Pragma("unroll")                                                              \
        for (int el_ = 0; el_ < 4; ++el_) {                                            \
            const size_t b_ = ((size_t)(((m_) * 4 + (ss_)) * 8 + eq * 4 + el_)) * 128; \
            dst_[el_ * 2]     = wp[b_];                                                \
            dst_[el_ * 2 + 1] = wp[b_ + 64];                                           \
        }                                                                              \
    } while (0)

// Pack W_linear||W_noise into MFMA B-fragment order (verified rounds 5-25)
__global__ __launch_bounds__(256)
void prep_w(const float* __restrict__ Wl, const float* __restrict__ Wn,
            ushort* __restrict__ wsB)
{
    const int t    = blockIdx.x * 256 + threadIdx.x;
    const int lane = t & 63;
    const int et   = (t >> 6) & 7;
    const int s    = t >> 9;
    const int e    = et * 16 + (lane & 15);
    const int k    = s * 32 + ((lane >> 4) * 8);
    const float* src = (e < EE) ? &Wl[(long)e * DD + k] : &Wn[(long)(e - EE) * DD + k];
    const float4 f0 = *reinterpret_cast<const float4*>(src);
    const float4 f1 = *reinterpret_cast<const float4*>(src + 4);
    const float f[8] = {f0.x, f0.y, f0.z, f0.w, f1.x, f1.y, f1.z, f1.w};
    uint hw[4], lw[4];
#pragma unroll
    for (int j = 0; j < 4; ++j) {
        ushort h0, l0, h1, l1;
        split_bf16(f[2 * j], h0, l0);
        split_bf16(f[2 * j + 1], h1, l1);
        hw[j] = (uint)h0 | ((uint)h1 << 16);
        lw[j] = (uint)l0 | ((uint)l1 << 16);
    }
    const size_t chunk = ((size_t)(s * 8 + et)) * 1024;
    *reinterpret_cast<uint4*>(&wsB[chunk + lane * 8])       = make_uint4(hw[0], hw[1], hw[2], hw[3]);
    *reinterpret_cast<uint4*>(&wsB[chunk + 512 + lane * 8]) = make_uint4(lw[0], lw[1], lw[2], lw[3]);
}

__global__ __launch_bounds__(NTH, 2)
void router_main(const float* __restrict__ x,
                 const float* __restrict__ noise,
                 const ushort* __restrict__ wsB,
                 const float* __restrict__ Wl, const float* __restrict__ bl,
                 const float* __restrict__ Wn, const float* __restrict__ bn,
                 float* __restrict__ out_router, float* __restrict__ out_idx)
{
    // [0,32K) xbuf0 | [32K,64K) xbuf1 ; post-loop res[64][129] aliases; x-row restage at [0,8K)
    __shared__ __align__(16) unsigned char smem[2 * XB];
    __shared__ float  tkv[TPB][KK];
    __shared__ int    tki[TPB][KK];
    __shared__ int    cand[TPB][10];
    __shared__ int    amb_list[TPB];
    __shared__ int    amb_count;
    __shared__ double dsh[20];

    const int tid  = threadIdx.x;
    const int lane = tid & 63;
    const int w    = tid >> 6;
    const int mh   = w >> 1;
    const int eq   = w & 1;
    const long tok0 = (long)blockIdx.x * TPB;
    if (tid == 0) amb_count = 0;

    const uint4* wp = reinterpret_cast<const uint4*>(wsB) + lane;

    f32x4 acc[2][4];
#pragma unroll
    for (int mt = 0; mt < 2; ++mt)
#pragma unroll
        for (int e = 0; e < 4; ++e) acc[mt][e] = {0.f, 0.f, 0.f, 0.f};

    uint4 W0[8], W1[8], W2[8], W3[8];
    STAGE(0, 0);
    LOADW(W0, 0, 0);
    LOADW(W1, 0, 1);
    __syncthreads();

    const int colr = lane & 15;
    const int krow = lane >> 4;

    for (int m = 0; m < NMEGA; ++m) {
        const int cur = m & 1;
        if (m + 1 < NMEGA) STAGE(m + 1, cur ^ 1);
        const unsigned char* xb = smem + cur * XB;
#pragma unroll
        for (int ss = 0; ss < 4; ++ss) {
            if (ss == 0)      LOADW(W2, m, 2);
            else if (ss == 1) LOADW(W3, m, 3);
            else if (ss == 2) { if (m + 1 < NMEGA) LOADW(W0, m + 1, 0); }
            else              { if (m + 1 < NMEGA) LOADW(W1, m + 1, 1); }

            short8 ah[2], al[2];
#pragma unroll
            for (int mt = 0; mt < 2; ++mt) {
                const int r = mh * 32 + mt * 16 + colr;
                const unsigned char* base = xb + r * 512;
                const int v0 = ss * 8 + krow * 2;
                const float4 f0 = *reinterpret_cast<const float4*>(base + ((v0 ^ (r & 7)) << 4));
                const float4 f1 = *reinterpret_cast<const float4*>(base + (((v0 + 1) ^ (r & 7)) << 4));
                conv_tile(f0, f1, ah[mt], al[mt]);
            }
            const uint4* Wc = (ss == 0) ? W0 : (ss == 1) ? W1 : (ss == 2) ? W2 : W3;
#pragma unroll
            for (int el = 0; el < 4; ++el) {
                const short8 bh  = __builtin_bit_cast(short8, Wc[el * 2]);
                const short8 bl2 = __builtin_bit_cast(short8, Wc[el * 2 + 1]);
                acc[0][el] = __builtin_amdgcn_mfma_f32_16x16x32_bf16(ah[0], bh,  acc[0][el], 0, 0, 0);
                acc[1][el] = __builtin_amdgcn_mfma_f32_16x16x32_bf16(ah[1], bh,  acc[1][el], 0, 0, 0);
                acc[0][el] = __builtin_amdgcn_mfma_f32_16x16x32_bf16(al[0], bh,  acc[0][el], 0, 0, 0);
                acc[1][el] = __builtin_amdgcn_mfma_f32_16x16x32_bf16(al[1], bh,  acc[1][el], 0, 0, 0);
                acc[0][el] = __builtin_amdgcn_mfma_f32_16x16x32_bf16(ah[0], bl2, acc[0][el], 0, 0, 0);
                acc[1][el] = __builtin_amdgcn_mfma_f32_16x16x32_bf16(ah[1], bl2, acc[1][el], 0, 0, 0);
            }
        }
        __syncthreads();
    }

    // ---------------- epilogue (res aliases dead stage buffers) ----------------
    float* res = reinterpret_cast<float*>(smem);   // [64][129]
    {
        // C/D layout (verified r5): col = lane&15 (expert), row = (lane>>4)*4 + reg
        const int rg = (lane >> 4) * 4;
#pragma unroll
        for (int mt = 0; mt < 2; ++mt)
#pragma unroll
            for (int el = 0; el < 4; ++el) {
                const int e = (eq * 4 + el) * 16 + colr;
                const float bias = (e < EE) ? bl[e] : bn[e - EE];
#pragma unroll
                for (int r = 0; r < 4; ++r)
                    RES(mh * 32 + mt * 16 + rg + r, e) = acc[mt][el][r] + bias;
            }
    }
    __syncthreads();

    // noisy = logits + noise * softplus(noise_logits); quad per token (same map as scan)
    {
        const int t  = tid >> 2;
        const int e0 = (tid & 3) * 16;
        const float* nrow = &noise[(tok0 + t) * (long)EE];
#pragma unroll 4
        for (int j = 0; j < 16; ++j) {
            const int e = e0 + j;
            const float z  = RES(t, EE + e);
            const float sp = fmaxf(z, 0.f) + log1pf(expf(-fabsf(z)));
            RES(t, e) = RES(t, e) + nrow[e] * sp;
        }
    }
    __syncthreads();

    // top-10 extraction: 4 lanes per token (wave-synchronous); strict > keeps lowest idx
    {
        const int t   = tid >> 2;
        const int sub = tid & 3;
        float lv[10]; int li[10];
#pragma unroll
        for (int k = 0; k < 10; ++k) {
            float best = -INFINITY;
            int bi = sub * 16;
#pragma unroll
            for (int j = 0; j < 16; ++j) {
                const int e = sub * 16 + j;
                const float v = RES(t, e);
                if (v > best) { best = v; bi = e; }
            }
#pragma unroll
            for (int m = 1; m < 4; m <<= 1) {
                const float ov = __shfl_xor(best, m, 64);
                const int   oi = __shfl_xor(bi, m, 64);
                if (ov > best || (ov == best && oi < bi)) { best = ov; bi = oi; }
            }
            lv[k] = best; li[k] = bi;
            if ((bi >> 4) == sub) RES(t, bi) = -INFINITY;   // owner knocks it out
        }
        bool amb = false;
#pragma unroll
        for (int k = 0; k < 9; ++k) amb |= (lv[k] - lv[k + 1] < TAU);
        const float mmax = lv[0];
        float p[KK];
        float sm = 0.f;
#pragma unroll
        for (int k = 0; k < KK; ++k) { p[k] = expf(lv[k] - mmax); sm += p[k]; }
        const float inv = 1.f / sm;
        if (sub == 0) {
#pragma unroll
            for (int k = 0; k < KK; ++k) { tkv[t][k] = p[k] * inv; tki[t][k] = li[k]; }
            if (amb) {
                const int pos = atomicAdd(&amb_count, 1);
                amb_list[pos] = t;
#pragma unroll
                for (int c = 0; c < 10; ++c) cand[t][c] = li[c];
            }
        }
    }
    __syncthreads();

    // fp64 recompute of flagged tokens, RESTRICTED to the fp32 top-10 candidates.
    // Only they can contest the output top-8 (gap >= TAU below is > 30 sigma safe).
    const int namb = amb_count;
    for (int a = 0; a < namb; ++a) {
        const int t = amb_list[a];
        {   // stage x row (8 KB) into smem[0..8K) — res rows 0..15 are dead
            const float4* xsrc = reinterpret_cast<const float4*>(&x[(tok0 + t) * (long)DD]);
            float4* xd = reinterpret_cast<float4*>(smem);
            xd[tid * 2]     = xsrc[tid * 2];
            xd[tid * 2 + 1] = xsrc[tid * 2 + 1];
        }
        __syncthreads();
        {   // 20 dots (10 experts x {Wl,Wn}), 8 lane-contiguous threads each
            const int g  = tid >> 3;
            const int gs = tid & 7;
            double dsum = 0.0;
            if (g < 20) {
                const int c = (g < 10) ? g : g - 10;
                const int e = cand[t][c];
                const float* wr = (g < 10) ? &Wl[(long)e * DD] : &Wn[(long)e * DD];
                const float* xs = reinterpret_cast<const float*>(smem);
                for (int k = gs * 4; k < DD; k += 32) {
                    const float4 xv = *reinterpret_cast<const float4*>(&xs[k]);
                    const float4 wv = *reinterpret_cast<const float4*>(&wr[k]);
                    dsum = fma((double)xv.x, (double)wv.x, dsum);
                    dsum = fma((double)xv.y, (double)wv.y, dsum);
                    dsum = fma((double)xv.z, (double)wv.z, dsum);
                    dsum = fma((double)xv.w, (double)wv.w, dsum);
                }
            }
#pragma unroll
            for (int m = 1; m < 8; m <<= 1) dsum += __shfl_xor(dsum, m, 64);
            if (g < 20 && (tid & 7) == 0) dsh[g] = dsum;
        }
        __syncthreads();
        if (tid < 64) {   // wave 0: fp64 noisy on 10 lanes + butterfly top-8 + softmax
            double val; int idx;
            if (tid < 10) {
                const int e = cand[t][tid];
                const double v  = dsh[tid] + (double)bl[e];
                const double z  = dsh[10 + tid] + (double)bn[e];
                const double sp = fmax(z, 0.0) + log1p(exp(-fabs(z)));
                val = v + (double)noise[(tok0 + t) * (long)EE + e] * sp;
                idx = e;
            } else { val = -INFINITY; idx = 64 + tid; }
            double sel[KK]; int sidx[KK];
#pragma unroll
            for (int k = 0; k < KK; ++k) {
                double mv = val; int mi = idx;
#pragma unroll
                for (int m = 1; m < 64; m <<= 1) {
                    const double ov = __shfl_xor(mv, m, 64);
                    const int   oi = __shfl_xor(mi, m, 64);
                    if (ov > mv || (ov == mv && oi < mi)) { mv = ov; mi = oi; }
                }
                sel[k] = mv; sidx[k] = mi;
                if (idx == mi) val = -INFINITY;
            }
            if (tid == 0) {
                const double mx = sel[0];
                double p[KK]; double sm = 0.0;
#pragma unroll
                for (int k = 0; k < KK; ++k) { p[k] = exp(sel[k] - mx); sm += p[k]; }
                const double inv = 1.0 / sm;
#pragma unroll
                for (int k = 0; k < KK; ++k) {
                    tkv[t][k] = (float)(p[k] * inv);
                    tki[t][k] = sidx[k];
                }
            }
        }
        __syncthreads();
    }

    // router output: compare-select scatter, coalesced float4 stores
    {
        const int t  = tid >> 2;
        const int e0 = (tid & 3) * 16;
        int   ki[KK];
        float kv[KK];
#pragma unroll
        for (int k = 0; k < KK; ++k) { ki[k] = tki[t][k]; kv[k] = tkv[t][k]; }
        float4 v[4];
        float* vf = reinterpret_cast<float*>(v);
#pragma unroll
        for (int j = 0; j < 16; ++j) {
            float val = 0.f;
#pragma unroll
            for (int k = 0; k < KK; ++k)
                val = (ki[k] == e0 + j) ? kv[k] : val;
            vf[j] = val;
        }
        float4* dst = reinterpret_cast<float4*>(&out_router[(tok0 + t) * (long)EE + e0]);
#pragma unroll
        for (int q = 0; q < 4; ++q) dst[q] = v[q];
    }
    // indices output, written as float32 values (whole d_out read as f32 by harness)
    {
        const int f = tid * 2;
        const int t = f >> 3;
        const int k0i = f & 7;
        out_idx[(tok0 + t) * (long)KK + k0i]     = (float)tki[t][k0i];
        out_idx[(tok0 + t) * (long)KK + k0i + 1] = (float)tki[t][k0i + 1];
    }
}

extern "C" void kernel_launch(void* const* d_in, const int* in_sizes, int n_in,
                              void* d_out, int out_size, void* d_ws, size_t ws_size,
                              hipStream_t stream) {
    const float* x     = (const float*)d_in[0];
    const float* noise = (const float*)d_in[1];
    const float* Wl    = (const float*)d_in[2];
    const float* bl    = (const float*)d_in[3];
    const float* Wn    = (const float*)d_in[4];
    const float* bn    = (const float*)d_in[5];

    const int M = in_sizes[0] / DD;            // B*S = 32768
    float* out_router = (float*)d_out;
    float* out_idx    = (float*)d_out + (long)M * EE;
    ushort* wsB = (ushort*)d_ws;               // 1 MiB fragment-packed W hi/lo

    hipLaunchKernelGGL(prep_w, dim3(128), dim3(256), 0, stream, Wl, Wn, wsB);
    hipLaunchKernelGGL(router_main, dim3(M / TPB), dim3(NTH), 0, stream,
                       x, noise, wsB, Wl, bl, Wn, bn, out_router, out_idx);
}